// Round 1
// baseline (98.976 us; speedup 1.0000x reference)
//
#include <hip/hip_runtime.h>

// SinePredictor:
//   s = h[edges[0]]; o = h[edges[1]]            [E,128] gathers
//   score = sin(s-o) @ W.T + b                  [E,1]
//   score = softmax over consecutive pairs      [E/2,2] -> [E,1]
//   out = concat(score, score > 0.5)            2*E floats
//
// One 64-lane wave handles one PAIR of edges:
//   lanes 0..31  -> edge 2p   (each lane loads one float4 = 16B of the row)
//   lanes 32..63 -> edge 2p+1
// Shuffle-reduce within each 32-lane half, exchange across halves for the
// 2-way softmax. W staged in registers (one float4 per lane position).

__global__ __launch_bounds__(256) void sine_predictor_kernel(
    const float* __restrict__ h,
    const int*   __restrict__ edges,   // [2, E] int32
    const float* __restrict__ W,       // [1, 128]
    const float* __restrict__ b,       // [1]
    float*       __restrict__ out,     // [2*E]: scores then mask
    int n_edges)
{
    const int lane = threadIdx.x & 63;
    const int sub  = lane & 31;   // position within half-wave (covers D=128 as 32 x float4)
    const int half = lane >> 5;   // which edge of the pair
    const int waves_per_block = blockDim.x >> 6;
    const int wave_in_block   = threadIdx.x >> 6;
    const int n_pairs = n_edges >> 1;

    // Stage W fragment + bias once (reused across grid-stride iterations).
    const float4 w4  = reinterpret_cast<const float4*>(W)[sub];
    const float bias = b[0];

    int pair = blockIdx.x * waves_per_block + wave_in_block;
    const int stride = gridDim.x * waves_per_block;

    for (; pair < n_pairs; pair += stride) {
        const int e   = 2 * pair + half;
        const int src = edges[e];            // broadcast within half-wave
        const int obj = edges[n_edges + e];

        const float4 s4 = reinterpret_cast<const float4*>(h + (size_t)src * 128)[sub];
        const float4 o4 = reinterpret_cast<const float4*>(h + (size_t)obj * 128)[sub];

        float part = sinf(s4.x - o4.x) * w4.x
                   + sinf(s4.y - o4.y) * w4.y
                   + sinf(s4.z - o4.z) * w4.z
                   + sinf(s4.w - o4.w) * w4.w;

        // Reduce across the 32-lane half (xor masks 1..16 stay within the half).
        #pragma unroll
        for (int m = 16; m >= 1; m >>= 1)
            part += __shfl_xor(part, m, 64);

        const float x     = part + bias;
        const float other = __shfl_xor(x, 32, 64);  // partner edge's score
        const float mx    = fmaxf(x, other);
        const float es    = __expf(x - mx);
        const float eo    = __expf(other - mx);
        const float p     = es / (es + eo);

        if (sub == 0) {
            out[e]           = p;
            out[n_edges + e] = (p > 0.5f) ? 1.0f : 0.0f;
        }
    }
}

extern "C" void kernel_launch(void* const* d_in, const int* in_sizes, int n_in,
                              void* d_out, int out_size, void* d_ws, size_t ws_size,
                              hipStream_t stream) {
    const float* h     = (const float*)d_in[0];
    const int*   edges = (const int*)d_in[1];
    const float* W     = (const float*)d_in[2];
    const float* b     = (const float*)d_in[3];
    float*       out   = (float*)d_out;

    const int n_edges = in_sizes[1] / 2;   // edges is [2, E]

    // 2048 blocks x 4 waves = 8192 waves = 256 CU x 32 waves/CU: full machine,
    // grid-stride over the 320k pairs.
    const int blocks = 2048;
    sine_predictor_kernel<<<blocks, 256, 0, stream>>>(h, edges, W, b, out, n_edges);
}

// Round 2
// 97.216 us; speedup vs baseline: 1.0181x; 1.0181x over previous
//
#include <hip/hip_runtime.h>

// SinePredictor:
//   s = h[edges[0]]; o = h[edges[1]]            [E,128] gathers
//   score = sin(s-o) @ W.T + b                  [E,1]
//   score = softmax over consecutive pairs      [E/2,2] -> [E,1]
//   out = concat(score, score > 0.5)            2*E floats
//
// One 64-lane wave handles one PAIR of edges:
//   lanes 0..31  -> edge 2p   (each lane loads one float4 = 16B of the row)
//   lanes 32..63 -> edge 2p+1
// Round 1: libm sinf was 85% VALUBusy -> use __sinf (v_sin_f32 hardware
// transcendental; |s-o| ~ N(0,2) is well inside its accurate range).
// Unroll grid-stride 2x for more gather MLP.

__device__ __forceinline__ float pair_score(
    const float* __restrict__ h,
    const int* __restrict__ edges,
    int n_edges, int e, int sub, const float4 w4)
{
    const int src = edges[e];
    const int obj = edges[n_edges + e];
    const float4 s4 = reinterpret_cast<const float4*>(h + (size_t)src * 128)[sub];
    const float4 o4 = reinterpret_cast<const float4*>(h + (size_t)obj * 128)[sub];
    float part = __sinf(s4.x - o4.x) * w4.x
               + __sinf(s4.y - o4.y) * w4.y
               + __sinf(s4.z - o4.z) * w4.z
               + __sinf(s4.w - o4.w) * w4.w;
    return part;
}

__device__ __forceinline__ void finish_pair(
    float part, float bias, int e, int n_edges, int sub,
    float* __restrict__ out)
{
    // Reduce across the 32-lane half (xor masks 1..16 stay within the half).
    #pragma unroll
    for (int m = 16; m >= 1; m >>= 1)
        part += __shfl_xor(part, m, 64);

    const float x     = part + bias;
    const float other = __shfl_xor(x, 32, 64);  // partner edge's score
    const float mx    = fmaxf(x, other);
    const float es    = __expf(x - mx);
    const float eo    = __expf(other - mx);
    const float p     = es / (es + eo);

    if (sub == 0) {
        out[e]           = p;
        out[n_edges + e] = (p > 0.5f) ? 1.0f : 0.0f;
    }
}

__global__ __launch_bounds__(256) void sine_predictor_kernel(
    const float* __restrict__ h,
    const int*   __restrict__ edges,   // [2, E] int32
    const float* __restrict__ W,       // [1, 128]
    const float* __restrict__ b,       // [1]
    float*       __restrict__ out,     // [2*E]: scores then mask
    int n_edges)
{
    const int lane = threadIdx.x & 63;
    const int sub  = lane & 31;   // position within half-wave (covers D=128 as 32 x float4)
    const int half = lane >> 5;   // which edge of the pair
    const int waves_per_block = blockDim.x >> 6;
    const int wave_in_block   = threadIdx.x >> 6;
    const int n_pairs = n_edges >> 1;

    const float4 w4  = reinterpret_cast<const float4*>(W)[sub];
    const float bias = b[0];

    const int wave_id = blockIdx.x * waves_per_block + wave_in_block;
    const int stride  = gridDim.x * waves_per_block;

    // 2x-unrolled grid-stride: iteration j handles pair indices
    // wave_id + (2j)*stride and wave_id + (2j+1)*stride.
    for (int pair = wave_id; pair < n_pairs; pair += 2 * stride) {
        const int e1    = 2 * pair + half;
        const int pair2 = pair + stride;
        const bool has2 = pair2 < n_pairs;

        float part1 = pair_score(h, edges, n_edges, e1, sub, w4);
        float part2 = 0.0f;
        int   e2    = 0;
        if (has2) {
            e2    = 2 * pair2 + half;
            part2 = pair_score(h, edges, n_edges, e2, sub, w4);
        }

        finish_pair(part1, bias, e1, n_edges, sub, out);
        if (has2)
            finish_pair(part2, bias, e2, n_edges, sub, out);
    }
}

extern "C" void kernel_launch(void* const* d_in, const int* in_sizes, int n_in,
                              void* d_out, int out_size, void* d_ws, size_t ws_size,
                              hipStream_t stream) {
    const float* h     = (const float*)d_in[0];
    const int*   edges = (const int*)d_in[1];
    const float* W     = (const float*)d_in[2];
    const float* b     = (const float*)d_in[3];
    float*       out   = (float*)d_out;

    const int n_edges = in_sizes[1] / 2;   // edges is [2, E]

    // 2048 blocks x 4 waves = 8192 waves = 256 CU x 32 waves/CU: full machine,
    // grid-stride over the 320k pairs.
    const int blocks = 2048;
    sine_predictor_kernel<<<blocks, 256, 0, stream>>>(h, edges, W, b, out, n_edges);
}